// Round 14
// baseline (496.369 us; speedup 1.0000x reference)
//
#include <hip/hip_runtime.h>
#include <hip/hip_bf16.h>

// ---------------------------------------------------------------------------
// CNN_quantize round 14: single-variable A/B on quant_v5 -- NT stores replaced
// by PLAIN float4 stores (r13 counters showed NT caused 1.22x write
// amplification: 430MB vs 354MB ideal; v4's plain stores measured exact).
// Everything else byte-identical to round 13.
//
// Output layout (floats): [0,1280) pred; [1280] extra_loss;
// [1281,1281+84934656) att(3,221184,128); [84935937] contrastive.
//
// Workspace (byte offsets):
//   xq    f32  @ 0           14,155,776 B   (128,3,96,96)
//   y1    bf16 @ 14,155,776  69,337,088 B   (128,92,92,32) NHWC
//   y2    bf16 @ 83,492,864  15,859,712 B   (128,44,44,32) NHWC
//   y3    bf16 @ 99,352,576   1,638,400 B   (128,20,20,16) NHWC
//   part  f32  @ 104,267,776  4,194,304 B
//   y4    f32  @ 108,462,080    262,144 B
//   wp2   bf16 @ 108,724,224     51,200 B
//   wp3   bf16 @ 108,775,424     25,600 B
//   cbn2  f32  @ 108,801,024      1,536 B
//   loss  f32  @ 108,802,560          4 B
//   wf1p  bf16 @ 108,802,624   6,553,600 B  (512,6400) NHWC k-order
// ---------------------------------------------------------------------------

#define NP 221184

typedef __attribute__((ext_vector_type(8)))  short  short8;   // 8 bf16
typedef __attribute__((ext_vector_type(16))) float  f32x16;
typedef __attribute__((ext_vector_type(4)))  float  f32x4;

// ---------------------------------------------------------------------- quant
// v5 structure (k-split 4 waves, exps in regs, block reduce, granule-XOR
// swizzled b128 stage transpose) with PLAIN float4 att stores.
__global__ __launch_bounds__(256) void quant_v5p(
    const float* __restrict__ x, const float* __restrict__ cb,
    const float* __restrict__ cbn2,
    float* __restrict__ att, float* __restrict__ xq, float* __restrict__ lossAcc)
{
  __shared__ float stage[4][64][32];   // 32 KB granule-swizzled
  __shared__ float sred[4][64];
  __shared__ float mred[4][64];
  __shared__ int   ired[4][64];

  const int tid  = threadIdx.x;
  const int wv   = tid >> 6;
  const int lane = tid & 63;
  const int n0   = blockIdx.x * 64;
  const int n    = n0 + lane;
  const int l7   = lane & 7;

  const float4* xp4 = (const float4*)(x + (size_t)n*16);
  float4 xa = xp4[0], xb = xp4[1], xc = xp4[2], xd = xp4[3];
  float xv[16] = {xa.x,xa.y,xa.z,xa.w, xb.x,xb.y,xb.z,xb.w,
                  xc.x,xc.y,xc.z,xc.w, xd.x,xd.y,xd.z,xd.w};
  float xn2 = 0.f;
#pragma unroll
  for (int d = 0; d < 16; ++d) xn2 += xv[d]*xv[d];

  float xqacc[16];
#pragma unroll
  for (int d = 0; d < 16; ++d) xqacc[d] = 0.f;
  float lossLocal = 0.f;

#pragma unroll 1
  for (int g = 0; g < 3; ++g) {
    const float* cg  = cb + g*2048 + wv*512;
    const float* c2g = cbn2 + g*128 + wv*32;

    float ex[32];
    float s = 0.f;
    float mv = 3.4e38f; int mi = 0;
#pragma unroll
    for (int kk = 0; kk < 32; ++kk) {
      const float4* cr = (const float4*)(cg + kk*16);
      float4 c0 = cr[0], c1 = cr[1], c2 = cr[2], c3 = cr[3];
      float p0 = fmaf(xv[0],c0.x, fmaf(xv[1],c0.y, fmaf(xv[2],c0.z, xv[3]*c0.w)));
      float p1 = fmaf(xv[4],c1.x, fmaf(xv[5],c1.y, fmaf(xv[6],c1.z, xv[7]*c1.w)));
      float p2 = fmaf(xv[8],c2.x, fmaf(xv[9],c2.y, fmaf(xv[10],c2.z, xv[11]*c2.w)));
      float p3 = fmaf(xv[12],c3.x, fmaf(xv[13],c3.y, fmaf(xv[14],c3.z, xv[15]*c3.w)));
      float dot = (p0+p1)+(p2+p3);
      float d2 = xn2 - 2.f*dot + c2g[kk];
      float e = __expf(-d2);
      ex[kk] = e;
      s += e;
      if (d2 < mv) { mv = d2; mi = wv*32 + kk; }   // strict < -> lowest k
    }

    __syncthreads();
    sred[wv][lane] = s;
    mred[wv][lane] = mv;
    ired[wv][lane] = mi;
    __syncthreads();
    float stot = (sred[0][lane] + sred[1][lane]) + (sred[2][lane] + sred[3][lane]);
    float bm = mred[0][lane]; int bi = ired[0][lane];
#pragma unroll
    for (int w = 1; w < 4; ++w) {
      float m2 = mred[w][lane];
      int   i2 = ired[w][lane];
      if (m2 < bm) { bm = m2; bi = i2; }
    }
    float inv = 1.f / stot;

#pragma unroll
    for (int j = 0; j < 8; ++j) {
      f32x4 v;
      v[0] = ex[4*j]   * inv;
      v[1] = ex[4*j+1] * inv;
      v[2] = ex[4*j+2] * inv;
      v[3] = ex[4*j+3] * inv;
      *(f32x4*)&stage[wv][lane][((j ^ l7) << 2)] = v;
    }
    __builtin_amdgcn_wave_barrier();

    {
      const int pr = lane >> 3;
      const int pg = l7 ^ pr;
      float* ab = att + ((size_t)g*NP + n0)*128 + wv*32;
#pragma unroll
      for (int i = 0; i < 8; ++i) {
        int p = pr + 8*i;
        f32x4 v = *(const f32x4*)&stage[wv][p][pg << 2];
        *(f32x4*)(ab + (size_t)p*128 + (l7 << 2)) = v;   // PLAIN store (A/B vs NT)
      }
    }
    __builtin_amdgcn_wave_barrier();

    if (wv == 0) {
      const float4* qr = (const float4*)(cb + g*2048 + bi*16);
      float4 q0 = qr[0], q1 = qr[1], q2 = qr[2], q3 = qr[3];
      float qv[16] = {q0.x,q0.y,q0.z,q0.w, q1.x,q1.y,q1.z,q1.w,
                      q2.x,q2.y,q2.z,q2.w, q3.x,q3.y,q3.z,q3.w};
#pragma unroll
      for (int d = 0; d < 16; ++d) {
        xqacc[d] += qv[d];
        float e = qv[d] - xv[d];
        lossLocal += e*e;
      }
    }
  }

  if (wv == 0) {
    float4* xqo = (float4*)(xq + (size_t)n*16);
    const float third = 1.f/3.f;
    xqo[0] = make_float4(xqacc[0]*third, xqacc[1]*third, xqacc[2]*third, xqacc[3]*third);
    xqo[1] = make_float4(xqacc[4]*third, xqacc[5]*third, xqacc[6]*third, xqacc[7]*third);
    xqo[2] = make_float4(xqacc[8]*third, xqacc[9]*third, xqacc[10]*third, xqacc[11]*third);
    xqo[3] = make_float4(xqacc[12]*third, xqacc[13]*third, xqacc[14]*third, xqacc[15]*third);
#pragma unroll
    for (int off = 32; off > 0; off >>= 1) lossLocal += __shfl_xor(lossLocal, off);
    if (lane == 0) atomicAdd(lossAcc, lossLocal);
  }
}

// ----------------------------------------------------------------- weight pack
__global__ __launch_bounds__(256) void pack_w_kernel(
    const float* __restrict__ w2, const float* __restrict__ w3,
    const float* __restrict__ cb,
    __hip_bfloat16* __restrict__ p2, __hip_bfloat16* __restrict__ p3,
    float* __restrict__ cbn2)
{
  int t = blockIdx.x*256 + threadIdx.x;
  if (t < 25600) {
    int ks = t >> 9, l = (t >> 3) & 63, j = t & 7;
    int ky = ks/10, kx = (ks%10)>>1, ih = ks & 1;
    int oc = l & 31, kh = l >> 5;
    int ic = ih*16 + kh*8 + j;
    p2[t] = __float2bfloat16(w2[((oc*32 + ic)*5 + ky)*5 + kx]);
  }
  if (t < 12800) {
    int ks = t >> 9, l = (t >> 3) & 63, j = t & 7;
    int ky = ks/5, kx = ks%5;
    int oc = l & 15, kh = l >> 4;
    int ic = kh*8 + j;
    p3[t] = __float2bfloat16(w3[((oc*32 + ic)*5 + ky)*5 + kx]);
  }
  if (t < 384) {
    float s = 0.f;
#pragma unroll
    for (int d = 0; d < 16; ++d) { float v = cb[t*16 + d]; s += v*v; }
    cbn2[t] = s;
  }
}

// fc1 weights -> NHWC k-order bf16: k' = (y*20+x)*16 + c ; src k = c*400+y*20+x
__global__ __launch_bounds__(256) void pack_wf1(
    const float* __restrict__ wf1, __hip_bfloat16* __restrict__ p)
{
  int t = blockIdx.x*256 + threadIdx.x;
  if (t < 512*6400) {
    int nn = t / 6400, k = t % 6400;
    int c = k & 15, yx = k >> 4;
    p[t] = __float2bfloat16(wf1[(size_t)nn*6400 + c*400 + yx]);
  }
}

// ---------------------------------------------------------------- conv1 direct
// (128,3,96,96) f32 NCHW -> (128,92,92,32) bf16 NHWC, relu.
// One 512-thr block per tile: all 32 oc, input staged ONCE. grid (36, 128).
__global__ __launch_bounds__(512) void conv1_kernel(
    const float* __restrict__ in, const float* __restrict__ wgt,
    const float* __restrict__ bias, __hip_bfloat16* __restrict__ out)
{
  int tile = blockIdx.x;
  int tx0 = (tile % 3) * 32, ty0 = (tile / 3) * 8;
  int n = blockIdx.y;

  int oc_l = threadIdx.x & 31;
  int slot = threadIdx.x >> 5;        // 0..15
  int rp = slot >> 2, cs = slot & 3;

  __shared__ __align__(16) float ins[3][12][36];   // 5184 B
  __shared__ float wl[32][77];                      // 9856 B
  __shared__ __hip_bfloat16 tb[8][32][32];          // 16384 B transpose buffer

  float acc[2][8];
#pragma unroll
  for (int r = 0; r < 2; ++r)
#pragma unroll
    for (int p = 0; p < 8; ++p) acc[r][p] = 0.f;

  for (int t = threadIdx.x; t < 3*12*36; t += 512) {
    int ic = t / (12*36); int r = t % (12*36); int ry = r / 36, rx = r % 36;
    int gy = ty0 + ry, gx = tx0 + rx;
    float v = 0.f;
    if (gy < 96 && gx < 96)
      v = in[(((size_t)n*3 + ic)*96 + gy)*96 + gx];
    ins[ic][ry][rx] = v;
  }
  for (int t = threadIdx.x; t < 32*75; t += 512) {
    int oc = t / 75, r = t % 75;
    wl[oc][r] = wgt[(size_t)oc*75 + r];
  }
  __syncthreads();

#pragma unroll 1
  for (int ic = 0; ic < 3; ++ic) {
#pragma unroll
    for (int ky = 0; ky < 5; ++ky) {
      float wv[5];
#pragma unroll
      for (int kx = 0; kx < 5; ++kx) wv[kx] = wl[oc_l][ic*25 + ky*5 + kx];
#pragma unroll
      for (int rr = 0; rr < 2; ++rr) {
        int ry = 2*rp + rr + ky;
        const float4* rowp = (const float4*)&ins[ic][ry][cs*8];
        float4 a = rowp[0], b = rowp[1], c = rowp[2];
        float iv[12] = {a.x,a.y,a.z,a.w, b.x,b.y,b.z,b.w, c.x,c.y,c.z,c.w};
#pragma unroll
        for (int kx = 0; kx < 5; ++kx)
#pragma unroll
          for (int px = 0; px < 8; ++px)
            acc[rr][px] += iv[px + kx] * wv[kx];
      }
    }
  }
  __syncthreads();

  float bv = bias[oc_l];
#pragma unroll
  for (int rr = 0; rr < 2; ++rr)
#pragma unroll
    for (int px = 0; px < 8; ++px)
      tb[2*rp + rr][cs*8 + px][oc_l] = __float2bfloat16(fmaxf(acc[rr][px] + bv, 0.f));
  __syncthreads();

  for (int t = threadIdx.x; t < 1024; t += 512) {
    int row = t >> 7, rem = t & 127, col = rem >> 2, q = rem & 3;
    int gy = ty0 + row, gx = tx0 + col;
    if (gy < 92 && gx < 92) {
      *(int4*)((char*)out + (((size_t)((n*92 + gy)*92 + gx))*32 + q*8)*2) =
          *(const int4*)((const char*)tb + t*16);
    }
  }
}

// ------------------------------------------------------------------ conv2 MFMA
__global__ __launch_bounds__(384) void conv2_mfma(
    const __hip_bfloat16* __restrict__ in, const __hip_bfloat16* __restrict__ wp,
    const float* __restrict__ bias, __hip_bfloat16* __restrict__ out)
{
  __shared__ __align__(16) char lds[8*100*64];   // 51200 B

  int n = blockIdx.y, rg = blockIdx.x;
  int oy0 = rg * 4;
  int tid = threadIdx.x;

  for (int t = tid; t < 3200; t += 384) {
    int row = t / 400, rem = t % 400, px = rem >> 2, g = rem & 3;
    int4 v = make_int4(0,0,0,0);
    if (px < 92)
      v = *(const int4*)(in + (((size_t)n*92 + oy0 + row)*92 + px)*32 + g*8);
    int sb = ((row*100 + px) << 6) + ((g ^ ((px >> 1) & 3)) << 4);
    *(int4*)(lds + sb) = v;
  }
  __syncthreads();

  int wv = tid >> 6, lane = tid & 63;
  int rp = wv & 1, cg = wv >> 1;
  int col = lane & 31, khalf = lane >> 5;
  int ixb = cg*32 + col;

  f32x16 acc0, acc1;
#pragma unroll
  for (int i = 0; i < 16; ++i) { acc0[i] = 0.f; acc1[i] = 0.f; }

#pragma unroll
  for (int ks = 0; ks < 50; ++ks) {
    const int ky = ks/10, kx = (ks%10)>>1, ih = ks & 1;
    short8 av = *(const short8*)(wp + ks*512 + lane*8);
    int ix = ixb + kx;
    int g  = (ih*2 + khalf) ^ ((ix >> 1) & 3);
    {
      int row = 2*rp + 0 + ky;
      short8 bv = *(const short8*)(lds + ((row*100 + ix) << 6) + (g << 4));
      acc0 = __builtin_amdgcn_mfma_f32_32x32x16_bf16(av, bv, acc0, 0, 0, 0);
    }
    {
      int row = 2*rp + 1 + ky;
      short8 bv = *(const short8*)(lds + ((row*100 + ix) << 6) + (g << 4));
      acc1 = __builtin_amdgcn_mfma_f32_32x32x16_bf16(av, bv, acc1, 0, 0, 0);
    }
  }
  __syncthreads();

  {
#pragma unroll
    for (int rq = 0; rq < 4; ++rq) {
      __hip_bfloat16 pv[4];
#pragma unroll
      for (int rr = 0; rr < 4; ++rr) {
        int r = rq*4 + rr;
        float m = fmaxf(acc0[r], acc1[r]);
        float o = __shfl_xor(m, 1);
        float p = fmaxf(m, o);
        int oc = (r & 3) + 8*(r >> 2) + 4*khalf;
        pv[rr] = __float2bfloat16(fmaxf(p + bias[oc], 0.f));
      }
      if ((lane & 1) == 0) {
        int pl = col >> 1;
        *(uint2*)(lds + wv*1024 + pl*64 + (8*rq + 4*khalf)*2) = *(const uint2*)pv;
      }
    }
  }
  __syncthreads();

  if (tid < 384) {
    int byte = tid * 16;
    int w = byte >> 10, r = byte & 1023;
    int pl = r >> 6, ocq = (r & 63) >> 4;
    int pr = rg*2 + (w & 1);
    int pc = (w >> 1)*16 + pl;
    if (pc < 44) {
      *(int4*)(out + (((size_t)n*44 + pr)*44 + pc)*32 + ocq*8) =
          *(const int4*)(lds + byte);
    }
  }
}

// ------------------------------------------------------------------ conv3 MFMA
__global__ __launch_bounds__(384) void conv3_mfma(
    const __hip_bfloat16* __restrict__ in, const __hip_bfloat16* __restrict__ wp,
    const float* __restrict__ bias, __hip_bfloat16* __restrict__ out)
{
  __shared__ __align__(16) char lds[8*52*64];   // 26624 B

  int n = blockIdx.y, rg = blockIdx.x;
  int oy0 = rg * 4;
  int tid = threadIdx.x;

  for (int t = tid; t < 1664; t += 384) {
    int row = t / 208, rem = t % 208, px = rem >> 2, g = rem & 3;
    int4 v = make_int4(0,0,0,0);
    if (px < 44)
      v = *(const int4*)(in + (((size_t)n*44 + oy0 + row)*44 + px)*32 + g*8);
    int sb = ((row*52 + px) << 6) + ((g ^ ((px >> 1) & 3)) << 4);
    *(int4*)(lds + sb) = v;
  }
  __syncthreads();

  int wv = tid >> 6, lane = tid & 63;
  int rp = wv & 1, cg = wv >> 1;
  int col = lane & 15, kq = lane >> 4;
  int ixb = cg*16 + col;

  f32x4 acc0, acc1;
#pragma unroll
  for (int i = 0; i < 4; ++i) { acc0[i] = 0.f; acc1[i] = 0.f; }

#pragma unroll
  for (int ks = 0; ks < 25; ++ks) {
    const int ky = ks/5, kx = ks%5;
    short8 av = *(const short8*)(wp + ks*512 + lane*8);
    int ix = ixb + kx;
    int g  = kq ^ ((ix >> 1) & 3);
    {
      int row = 2*rp + 0 + ky;
      short8 bv = *(const short8*)(lds + ((row*52 + ix) << 6) + (g << 4));
      acc0 = __builtin_amdgcn_mfma_f32_16x16x32_bf16(av, bv, acc0, 0, 0, 0);
    }
    {
      int row = 2*rp + 1 + ky;
      short8 bv = *(const short8*)(lds + ((row*52 + ix) << 6) + (g << 4));
      acc1 = __builtin_amdgcn_mfma_f32_16x16x32_bf16(av, bv, acc1, 0, 0, 0);
    }
  }
  __syncthreads();

  {
    __hip_bfloat16 pv[4];
#pragma unroll
    for (int r = 0; r < 4; ++r) {
      float m = fmaxf(acc0[r], acc1[r]);
      float o = __shfl_xor(m, 1);
      float p = fmaxf(m, o);
      int oc = kq*4 + r;
      pv[r] = __float2bfloat16(fmaxf(p + bias[oc], 0.f));
    }
    if ((lane & 1) == 0) {
      int pl = col >> 1;
      *(uint2*)(lds + wv*256 + pl*32 + kq*8) = *(const uint2*)pv;
    }
  }
  __syncthreads();

  if (tid < 96) {
    int byte = tid * 16;
    int w = byte >> 8, r = byte & 255;
    int pl = r >> 5, half = (r & 31) >> 4;
    int pr = rg*2 + (w & 1);
    int pc = (w >> 1)*8 + pl;
    if (pc < 20) {
      *(int4*)(out + (((size_t)n*20 + pr)*20 + pc)*16 + half*8) =
          *(const int4*)(lds + byte);
    }
  }
}

// ------------------------------------------------------------------------ fc1
// X = y3 bf16 NHWC (k' = (y*20+x)*16+c), W = wf1p bf16 same k-order.
__global__ __launch_bounds__(256) void fc1_partial(
    const __hip_bfloat16* __restrict__ x, const __hip_bfloat16* __restrict__ w,
    float* __restrict__ part)
{
  constexpr int KC = 6400 / 16;   // 400
  __shared__ float xl[128][16];
  __shared__ float wlds[32][17];
  int nt = blockIdx.x, ks = blockIdx.y;
  int k0 = ks * KC;
  int nl = threadIdx.x & 31;
  int mg = threadIdx.x >> 5;
  float acc[16];
#pragma unroll
  for (int j = 0; j < 16; ++j) acc[j] = 0.f;

  for (int kb = 0; kb < KC; kb += 16) {
    for (int t = threadIdx.x; t < 128*16; t += 256) {
      int m = t >> 4, kk = t & 15;
      xl[m][kk] = __bfloat162float(x[(size_t)m*6400 + k0 + kb + kk]);
    }
    for (int t = threadIdx.x; t < 32*16; t += 256) {
      int nn = t >> 4, kk = t & 15;
      wlds[nn][kk] = __bfloat162float(w[(size_t)(nt*32 + nn)*6400 + k0 + kb + kk]);
    }
    __syncthreads();
#pragma unroll
    for (int kk = 0; kk < 16; ++kk) {
      float wvv = wlds[nl][kk];
#pragma unroll
      for (int j = 0; j < 16; ++j)
        acc[j] += xl[mg + 8*j][kk] * wvv;
    }
    __syncthreads();
  }
#pragma unroll
  for (int j = 0; j < 16; ++j) {
    int m = mg + 8*j;
    part[((size_t)ks*128 + m)*512 + nt*32 + nl] = acc[j];
  }
}

__global__ __launch_bounds__(256) void fc1_reduce(
    const float* __restrict__ part, const float* __restrict__ bias,
    float* __restrict__ y4)
{
  int o = blockIdx.x*256 + threadIdx.x;
  int nn = o & 511;
  float s = 0.f;
#pragma unroll
  for (int ks = 0; ks < 16; ++ks)
    s += part[(size_t)ks*65536 + o];
  y4[o] = fmaxf(s + bias[nn], 0.f);
}

// ------------------------------------------------------------------------ fc2
__global__ __launch_bounds__(256) void fc2_kernel(
    const float* __restrict__ y4, const float* __restrict__ w2,
    const float* __restrict__ b2, float* __restrict__ pred)
{
  int o = blockIdx.x*256 + threadIdx.x;
  if (o >= 1280) return;
  int m = o / 10, c = o % 10;
  float s = 0.f;
  const float* yr = y4 + (size_t)m*512;
  const float* wr = w2 + (size_t)c*512;
#pragma unroll 8
  for (int k = 0; k < 512; ++k) s += yr[k]*wr[k];
  pred[o] = s + b2[c];
}

// -------------------------------------------------------------------- epilogue
__global__ void finalize_kernel(const float* __restrict__ lossAcc,
                                float* __restrict__ out)
{
  out[1280] = 2.f * (*lossAcc) / 10616832.f;
  out[84935937] = 0.f;
}

// ---------------------------------------------------------------------- launch
extern "C" void kernel_launch(void* const* d_in, const int* in_sizes, int n_in,
                              void* d_out, int out_size, void* d_ws, size_t ws_size,
                              hipStream_t stream)
{
  const float* x   = (const float*)d_in[0];
  const float* cb  = (const float*)d_in[1];
  const float* w1  = (const float*)d_in[2];
  const float* b1  = (const float*)d_in[3];
  const float* w2  = (const float*)d_in[4];
  const float* b2  = (const float*)d_in[5];
  const float* w3  = (const float*)d_in[6];
  const float* b3  = (const float*)d_in[7];
  const float* wf1 = (const float*)d_in[8];
  const float* bf1 = (const float*)d_in[9];
  const float* wf2 = (const float*)d_in[10];
  const float* bf2 = (const float*)d_in[11];

  float* out = (float*)d_out;
  char*  ws  = (char*)d_ws;

  float*          xq   = (float*)         (ws + 0);
  __hip_bfloat16* y1   = (__hip_bfloat16*)(ws + 14155776);
  __hip_bfloat16* y2   = (__hip_bfloat16*)(ws + 83492864);
  __hip_bfloat16* y3   = (__hip_bfloat16*)(ws + 99352576);
  float*          part = (float*)         (ws + 104267776);
  float*          y4   = (float*)         (ws + 108462080);
  __hip_bfloat16* wp2  = (__hip_bfloat16*)(ws + 108724224);
  __hip_bfloat16* wp3  = (__hip_bfloat16*)(ws + 108775424);
  float*          cbn2 = (float*)         (ws + 108801024);
  float*          loss = (float*)         (ws + 108802560);
  __hip_bfloat16* wf1p = (__hip_bfloat16*)(ws + 108802624);

  hipMemsetAsync(loss, 0, sizeof(float), stream);

  pack_w_kernel<<<100, 256, 0, stream>>>(w2, w3, cb, wp2, wp3, cbn2);
  pack_wf1<<<12800, 256, 0, stream>>>(wf1, wf1p);

  quant_v5p<<<3456, 256, 0, stream>>>(x, cb, cbn2, out + 1281, xq, loss);

  conv1_kernel<<<dim3(36, 128), 512, 0, stream>>>(xq, w1, b1, y1);
  conv2_mfma<<<dim3(22, 128), 384, 0, stream>>>(y1, wp2, b2, y2);
  conv3_mfma<<<dim3(10, 128), 384, 0, stream>>>(y2, wp3, b3, y3);

  fc1_partial<<<dim3(16, 16), 256, 0, stream>>>(y3, wf1p, part);
  fc1_reduce<<<256, 256, 0, stream>>>(part, bf1, y4);
  fc2_kernel<<<5, 256, 0, stream>>>(y4, wf2, bf2, out);

  finalize_kernel<<<1, 1, 0, stream>>>(loss, out);
}

// Round 15
// 398.718 us; speedup vs baseline: 1.2449x; 1.2449x over previous
//
#include <hip/hip_runtime.h>
#include <hip/hip_bf16.h>

// ---------------------------------------------------------------------------
// CNN_quantize round 15: quant_mfma = v5 structure but the distance pass is
// MFMA (dots = CB(32x16) @ X^T(16x32) per tile, bf16). r11/r14 evidence:
// v5's 230us = ~190us scalar dot/reduce + ~40us stores; MFMA removes the
// compute term. Reduce/stage/NT-store machinery identical to v5 (r13).
// Tail identical to r13. cbp packed into the 'part' region (free until fc1).
//
// Output layout (floats): [0,1280) pred; [1280] extra_loss;
// [1281,1281+84934656) att(3,221184,128); [84935937] contrastive.
//
// Workspace (byte offsets):
//   xq    f32  @ 0           14,155,776 B
//   y1    bf16 @ 14,155,776  69,337,088 B   (128,92,92,32) NHWC
//   y2    bf16 @ 83,492,864  15,859,712 B   (128,44,44,32) NHWC
//   y3    bf16 @ 99,352,576   1,638,400 B   (128,20,20,16) NHWC
//   part  f32  @ 104,267,776  4,194,304 B   (cbp bf16 12,288 B lives here
//                                            until fc1_partial overwrites)
//   y4    f32  @ 108,462,080    262,144 B
//   wp2   bf16 @ 108,724,224     51,200 B
//   wp3   bf16 @ 108,775,424     25,600 B
//   cbn2  f32  @ 108,801,024      1,536 B
//   loss  f32  @ 108,802,560          4 B
//   wf1p  bf16 @ 108,802,624   6,553,600 B
// ---------------------------------------------------------------------------

#define NP 221184

typedef __attribute__((ext_vector_type(8)))  short  short8;   // 8 bf16
typedef __attribute__((ext_vector_type(16))) float  f32x16;
typedef __attribute__((ext_vector_type(4)))  float  f32x4;

// ---------------------------------------------------------------------- quant
// Grid 3456 x 256 (4 waves; block = 64 patches). Wave wv owns codes
// [wv*32, wv*32+32). Dots via mfma_f32_32x32x16_bf16: A = cbp fragment
// (code row = lane&31, k = (lane>>5)*8+j  -- layout proven by conv2's wp2),
// B = patches (col = lane&31, same k mapping), two tiles (patches 0-31,32-63).
// C layout: col = lane&31, row = (reg&3)+8*(reg>>2)+4*(lane>>5).
// t = c2 - 2*dot (xn2-cancelled); exp/sum/argmin -> xor32 -> LDS cross-wave.
// Stage/transpose/NT stores byte-identical to v5.
__global__ __launch_bounds__(256) void quant_mfma(
    const float* __restrict__ x, const float* __restrict__ cb,
    const __hip_bfloat16* __restrict__ cbp, const float* __restrict__ cbn2,
    float* __restrict__ att, float* __restrict__ xq, float* __restrict__ lossAcc)
{
  __shared__ float stage[4][64][32];   // 32 KB granule-swizzled
  __shared__ float sred[4][64];
  __shared__ float mred[4][64];
  __shared__ int   ired[4][64];

  const int tid  = threadIdx.x;
  const int wv   = tid >> 6;
  const int lane = tid & 63;
  const int col  = lane & 31;
  const int hi   = lane >> 5;
  const int l7   = lane & 7;
  const int n0   = blockIdx.x * 64;
  const int n    = n0 + lane;          // this lane's patch for reduce/xq

  // xv for the xq/loss epilogue (patch = lane)
  const float4* xp4 = (const float4*)(x + (size_t)n*16);
  float4 xa = xp4[0], xb = xp4[1], xc = xp4[2], xd = xp4[3];
  float xv[16] = {xa.x,xa.y,xa.z,xa.w, xb.x,xb.y,xb.z,xb.w,
                  xc.x,xc.y,xc.z,xc.w, xd.x,xd.y,xd.z,xd.w};

  // B fragments: tile0 = patch n0+col, tile1 = patch n0+32+col; k = hi*8..+7
  short8 bf0, bf1;
  {
    __attribute__((aligned(16))) __hip_bfloat16 tmp[8];
    const float* p0 = x + (size_t)(n0 + col)*16 + hi*8;
    float4 u = *(const float4*)p0, v = *(const float4*)(p0 + 4);
    tmp[0]=__float2bfloat16(u.x); tmp[1]=__float2bfloat16(u.y);
    tmp[2]=__float2bfloat16(u.z); tmp[3]=__float2bfloat16(u.w);
    tmp[4]=__float2bfloat16(v.x); tmp[5]=__float2bfloat16(v.y);
    tmp[6]=__float2bfloat16(v.z); tmp[7]=__float2bfloat16(v.w);
    bf0 = *(const short8*)tmp;
    const float* p1 = x + (size_t)(n0 + 32 + col)*16 + hi*8;
    float4 u1 = *(const float4*)p1, v1 = *(const float4*)(p1 + 4);
    tmp[0]=__float2bfloat16(u1.x); tmp[1]=__float2bfloat16(u1.y);
    tmp[2]=__float2bfloat16(u1.z); tmp[3]=__float2bfloat16(u1.w);
    tmp[4]=__float2bfloat16(v1.x); tmp[5]=__float2bfloat16(v1.y);
    tmp[6]=__float2bfloat16(v1.z); tmp[7]=__float2bfloat16(v1.w);
    bf1 = *(const short8*)tmp;
  }

  float xqacc[16];
#pragma unroll
  for (int d = 0; d < 16; ++d) xqacc[d] = 0.f;
  float lossLocal = 0.f;

#pragma unroll 1
  for (int g = 0; g < 3; ++g) {
    const float* c2g = cbn2 + g*128 + wv*32;

    short8 af = *(const short8*)(cbp + ((size_t)(g*4 + wv)*64 + lane)*8);
    f32x16 zacc;
#pragma unroll
    for (int i = 0; i < 16; ++i) zacc[i] = 0.f;
    f32x16 acc0 = __builtin_amdgcn_mfma_f32_32x32x16_bf16(af, bf0, zacc, 0, 0, 0);
    f32x16 acc1 = __builtin_amdgcn_mfma_f32_32x32x16_bf16(af, bf1, zacc, 0, 0, 0);

    float e0[16], e1[16];
    float s0 = 0.f, s1 = 0.f;
    float bm0 = 3.4e38f, bm1 = 3.4e38f;
    int   bi0 = 0, bi1 = 0;
#pragma unroll
    for (int r = 0; r < 16; ++r) {
      const int row = (r & 3) + 8*(r >> 2) + 4*hi;
      const int k   = wv*32 + row;
      float c2 = c2g[row];
      float t0 = fmaf(-2.f, acc0[r], c2);
      float t1 = fmaf(-2.f, acc1[r], c2);
      float q0 = __expf(-t0);
      float q1 = __expf(-t1);
      e0[r] = q0; e1[r] = q1;
      s0 += q0; s1 += q1;
      if (t0 < bm0 || (t0 == bm0 && k < bi0)) { bm0 = t0; bi0 = k; }
      if (t1 < bm1 || (t1 == bm1 && k < bi1)) { bm1 = t1; bi1 = k; }
    }

    // combine the two half-lanes of each patch (lanes l and l^32 share col)
    s0 += __shfl_xor(s0, 32);
    s1 += __shfl_xor(s1, 32);
    {
      float om = __shfl_xor(bm0, 32); int oi = __shfl_xor(bi0, 32);
      if (om < bm0 || (om == bm0 && oi < bi0)) { bm0 = om; bi0 = oi; }
      om = __shfl_xor(bm1, 32); oi = __shfl_xor(bi1, 32);
      if (om < bm1 || (om == bm1 && oi < bi1)) { bm1 = om; bi1 = oi; }
    }
    // this lane's patch (= lane) lives in tile hi
    float sM  = hi ? s1 : s0;
    float bmM = hi ? bm1 : bm0;
    int   biM = hi ? bi1 : bi0;

    __syncthreads();                 // previous group's reduce reads complete
    sred[wv][lane] = sM;
    mred[wv][lane] = bmM;
    ired[wv][lane] = biM;
    __syncthreads();
    float stot = (sred[0][lane] + sred[1][lane]) + (sred[2][lane] + sred[3][lane]);
    float bm = mred[0][lane]; int bi = ired[0][lane];
#pragma unroll
    for (int w = 1; w < 4; ++w) {
      float m2 = mred[w][lane];
      int   i2 = ired[w][lane];
      if (m2 < bm) { bm = m2; bi = i2; }   // ascending wave = ascending k
    }
    float invL = 1.f / stot;
    float inv0 = __shfl(invL, col);        // patch col      (tile 0)
    float inv1 = __shfl(invL, col + 32);   // patch col+32   (tile 1)

    // stage writes: 4 b128 per tile; granule gl = run*2+hi covers rows
    // run*8+4hi..+3 == regs run*4..run*4+3 (contiguous). phys = gl ^ (p&7).
#pragma unroll
    for (int run = 0; run < 4; ++run) {
      const int gl = run*2 + hi;
      f32x4 v;
      v[0] = e0[run*4+0]*inv0; v[1] = e0[run*4+1]*inv0;
      v[2] = e0[run*4+2]*inv0; v[3] = e0[run*4+3]*inv0;
      *(f32x4*)&stage[wv][col][(gl ^ (col & 7)) << 2] = v;
      const int p1 = col + 32;
      f32x4 w4;
      w4[0] = e1[run*4+0]*inv1; w4[1] = e1[run*4+1]*inv1;
      w4[2] = e1[run*4+2]*inv1; w4[3] = e1[run*4+3]*inv1;
      *(f32x4*)&stage[wv][p1][(gl ^ (p1 & 7)) << 2] = w4;
    }
    __builtin_amdgcn_wave_barrier();

    // b128 transpose read + NT store (v5 verbatim)
    {
      const int pr = lane >> 3;
      const int pg = l7 ^ pr;
      float* ab = att + ((size_t)g*NP + n0)*128 + wv*32;
#pragma unroll
      for (int i = 0; i < 8; ++i) {
        int p = pr + 8*i;
        f32x4 v = *(const f32x4*)&stage[wv][p][pg << 2];
        __builtin_nontemporal_store(v, (f32x4*)(ab + (size_t)p*128 + (l7 << 2)));
      }
    }
    __builtin_amdgcn_wave_barrier();

    if (wv == 0) {
      const float4* qr = (const float4*)(cb + g*2048 + bi*16);
      float4 q0 = qr[0], q1 = qr[1], q2 = qr[2], q3 = qr[3];
      float qv[16] = {q0.x,q0.y,q0.z,q0.w, q1.x,q1.y,q1.z,q1.w,
                      q2.x,q2.y,q2.z,q2.w, q3.x,q3.y,q3.z,q3.w};
#pragma unroll
      for (int d = 0; d < 16; ++d) {
        xqacc[d] += qv[d];
        float e = qv[d] - xv[d];
        lossLocal += e*e;
      }
    }
  }

  if (wv == 0) {
    float4* xqo = (float4*)(xq + (size_t)n*16);
    const float third = 1.f/3.f;
    xqo[0] = make_float4(xqacc[0]*third, xqacc[1]*third, xqacc[2]*third, xqacc[3]*third);
    xqo[1] = make_float4(xqacc[4]*third, xqacc[5]*third, xqacc[6]*third, xqacc[7]*third);
    xqo[2] = make_float4(xqacc[8]*third, xqacc[9]*third, xqacc[10]*third, xqacc[11]*third);
    xqo[3] = make_float4(xqacc[12]*third, xqacc[13]*third, xqacc[14]*third, xqacc[15]*third);
#pragma unroll
    for (int off = 32; off > 0; off >>= 1) lossLocal += __shfl_xor(lossLocal, off);
    if (lane == 0) atomicAdd(lossAcc, lossLocal);
  }
}

// ----------------------------------------------------------------- weight pack
// wp2/wp3 as before; cbn2 = row norms; cbp = MFMA A-frags of cb:
// cbp[((g*4+ct)*64 + l)*8 + j] = cb[g][ct*32 + (l&31)][(l>>5)*8 + j]
__global__ __launch_bounds__(256) void pack_w_kernel(
    const float* __restrict__ w2, const float* __restrict__ w3,
    const float* __restrict__ cb,
    __hip_bfloat16* __restrict__ p2, __hip_bfloat16* __restrict__ p3,
    float* __restrict__ cbn2, __hip_bfloat16* __restrict__ cbp)
{
  int t = blockIdx.x*256 + threadIdx.x;
  if (t < 25600) {
    int ks = t >> 9, l = (t >> 3) & 63, j = t & 7;
    int ky = ks/10, kx = (ks%10)>>1, ih = ks & 1;
    int oc = l & 31, kh = l >> 5;
    int ic = ih*16 + kh*8 + j;
    p2[t] = __float2bfloat16(w2[((oc*32 + ic)*5 + ky)*5 + kx]);
  }
  if (t < 12800) {
    int ks = t >> 9, l = (t >> 3) & 63, j = t & 7;
    int ky = ks/5, kx = ks%5;
    int oc = l & 15, kh = l >> 4;
    int ic = kh*8 + j;
    p3[t] = __float2bfloat16(w3[((oc*32 + ic)*5 + ky)*5 + kx]);
  }
  if (t < 384) {
    float s = 0.f;
#pragma unroll
    for (int d = 0; d < 16; ++d) { float v = cb[t*16 + d]; s += v*v; }
    cbn2[t] = s;
  }
  if (t < 6144) {
    int g = t >> 11, r = t & 2047;
    int ct = r >> 9, l = (r >> 3) & 63, j = r & 7;
    int code = ct*32 + (l & 31);
    int d = (l >> 5)*8 + j;
    cbp[t] = __float2bfloat16(cb[((size_t)g*128 + code)*16 + d]);
  }
}

// fc1 weights -> NHWC k-order bf16
__global__ __launch_bounds__(256) void pack_wf1(
    const float* __restrict__ wf1, __hip_bfloat16* __restrict__ p)
{
  int t = blockIdx.x*256 + threadIdx.x;
  if (t < 512*6400) {
    int nn = t / 6400, k = t % 6400;
    int c = k & 15, yx = k >> 4;
    p[t] = __float2bfloat16(wf1[(size_t)nn*6400 + c*400 + yx]);
  }
}

// ---------------------------------------------------------------- conv1 direct
// (128,3,96,96) f32 NCHW -> (128,92,92,32) bf16 NHWC, relu. 512 thr, 32 oc.
__global__ __launch_bounds__(512) void conv1_kernel(
    const float* __restrict__ in, const float* __restrict__ wgt,
    const float* __restrict__ bias, __hip_bfloat16* __restrict__ out)
{
  int tile = blockIdx.x;
  int tx0 = (tile % 3) * 32, ty0 = (tile / 3) * 8;
  int n = blockIdx.y;

  int oc_l = threadIdx.x & 31;
  int slot = threadIdx.x >> 5;        // 0..15
  int rp = slot >> 2, cs = slot & 3;

  __shared__ __align__(16) float ins[3][12][36];
  __shared__ float wl[32][77];
  __shared__ __hip_bfloat16 tb[8][32][32];

  float acc[2][8];
#pragma unroll
  for (int r = 0; r < 2; ++r)
#pragma unroll
    for (int p = 0; p < 8; ++p) acc[r][p] = 0.f;

  for (int t = threadIdx.x; t < 3*12*36; t += 512) {
    int ic = t / (12*36); int r = t % (12*36); int ry = r / 36, rx = r % 36;
    int gy = ty0 + ry, gx = tx0 + rx;
    float v = 0.f;
    if (gy < 96 && gx < 96)
      v = in[(((size_t)n*3 + ic)*96 + gy)*96 + gx];
    ins[ic][ry][rx] = v;
  }
  for (int t = threadIdx.x; t < 32*75; t += 512) {
    int oc = t / 75, r = t % 75;
    wl[oc][r] = wgt[(size_t)oc*75 + r];
  }
  __syncthreads();

#pragma unroll 1
  for (int ic = 0; ic < 3; ++ic) {
#pragma unroll
    for (int ky = 0; ky < 5; ++ky) {
      float wv[5];
#pragma unroll
      for (int kx = 0; kx < 5; ++kx) wv[kx] = wl[oc_l][ic*25 + ky*5 + kx];
#pragma unroll
      for (int rr = 0; rr < 2; ++rr) {
        int ry = 2*rp + rr + ky;
        const float4* rowp = (const float4*)&ins[ic][ry][cs*8];
        float4 a = rowp[0], b = rowp[1], c = rowp[2];
        float iv[12] = {a.x,a.y,a.z,a.w, b.x,b.y,b.z,b.w, c.x,c.y,c.z,c.w};
#pragma unroll
        for (int kx = 0; kx < 5; ++kx)
#pragma unroll
          for (int px = 0; px < 8; ++px)
            acc[rr][px] += iv[px + kx] * wv[kx];
      }
    }
  }
  __syncthreads();

  float bv = bias[oc_l];
#pragma unroll
  for (int rr = 0; rr < 2; ++rr)
#pragma unroll
    for (int px = 0; px < 8; ++px)
      tb[2*rp + rr][cs*8 + px][oc_l] = __float2bfloat16(fmaxf(acc[rr][px] + bv, 0.f));
  __syncthreads();

  for (int t = threadIdx.x; t < 1024; t += 512) {
    int row = t >> 7, rem = t & 127, col = rem >> 2, q = rem & 3;
    int gy = ty0 + row, gx = tx0 + col;
    if (gy < 92 && gx < 92) {
      *(int4*)((char*)out + (((size_t)((n*92 + gy)*92 + gx))*32 + q*8)*2) =
          *(const int4*)((const char*)tb + t*16);
    }
  }
}

// ------------------------------------------------------------------ conv2 MFMA
__global__ __launch_bounds__(384) void conv2_mfma(
    const __hip_bfloat16* __restrict__ in, const __hip_bfloat16* __restrict__ wp,
    const float* __restrict__ bias, __hip_bfloat16* __restrict__ out)
{
  __shared__ __align__(16) char lds[8*100*64];   // 51200 B

  int n = blockIdx.y, rg = blockIdx.x;
  int oy0 = rg * 4;
  int tid = threadIdx.x;

  for (int t = tid; t < 3200; t += 384) {
    int row = t / 400, rem = t % 400, px = rem >> 2, g = rem & 3;
    int4 v = make_int4(0,0,0,0);
    if (px < 92)
      v = *(const int4*)(in + (((size_t)n*92 + oy0 + row)*92 + px)*32 + g*8);
    int sb = ((row*100 + px) << 6) + ((g ^ ((px >> 1) & 3)) << 4);
    *(int4*)(lds + sb) = v;
  }
  __syncthreads();

  int wv = tid >> 6, lane = tid & 63;
  int rp = wv & 1, cg = wv >> 1;
  int col = lane & 31, khalf = lane >> 5;
  int ixb = cg*32 + col;

  f32x16 acc0, acc1;
#pragma unroll
  for (int i = 0; i < 16; ++i) { acc0[i] = 0.f; acc1[i] = 0.f; }

#pragma unroll
  for (int ks = 0; ks < 50; ++ks) {
    const int ky = ks/10, kx = (ks%10)>>1, ih = ks & 1;
    short8 av = *(const short8*)(wp + ks*512 + lane*8);
    int ix = ixb + kx;
    int g  = (ih*2 + khalf) ^ ((ix >> 1) & 3);
    {
      int row = 2*rp + 0 + ky;
      short8 bv = *(const short8*)(lds + ((row*100 + ix) << 6) + (g << 4));
      acc0 = __builtin_amdgcn_mfma_f32_32x32x16_bf16(av, bv, acc0, 0, 0, 0);
    }
    {
      int row = 2*rp + 1 + ky;
      short8 bv = *(const short8*)(lds + ((row*100 + ix) << 6) + (g << 4));
      acc1 = __builtin_amdgcn_mfma_f32_32x32x16_bf16(av, bv, acc1, 0, 0, 0);
    }
  }
  __syncthreads();

  {
#pragma unroll
    for (int rq = 0; rq < 4; ++rq) {
      __hip_bfloat16 pv[4];
#pragma unroll
      for (int rr = 0; rr < 4; ++rr) {
        int r = rq*4 + rr;
        float m = fmaxf(acc0[r], acc1[r]);
        float o = __shfl_xor(m, 1);
        float p = fmaxf(m, o);
        int oc = (r & 3) + 8*(r >> 2) + 4*khalf;
        pv[rr] = __float2bfloat16(fmaxf(p + bias[oc], 0.f));
      }
      if ((lane & 1) == 0) {
        int pl = col >> 1;
        *(uint2*)(lds + wv*1024 + pl*64 + (8*rq + 4*khalf)*2) = *(const uint2*)pv;
      }
    }
  }
  __syncthreads();

  if (tid < 384) {
    int byte = tid * 16;
    int w = byte >> 10, r = byte & 1023;
    int pl = r >> 6, ocq = (r & 63) >> 4;
    int pr = rg*2 + (w & 1);
    int pc = (w >> 1)*16 + pl;
    if (pc < 44) {
      *(int4*)(out + (((size_t)n*44 + pr)*44 + pc)*32 + ocq*8) =
          *(const int4*)(lds + byte);
    }
  }
}

// ------------------------------------------------------------------ conv3 MFMA
__global__ __launch_bounds__(384) void conv3_mfma(
    const __hip_bfloat16* __restrict__ in, const __hip_bfloat16* __restrict__ wp,
    const float* __restrict__ bias, __hip_bfloat16* __restrict__ out)
{
  __shared__ __align__(16) char lds[8*52*64];   // 26624 B

  int n = blockIdx.y, rg = blockIdx.x;
  int oy0 = rg * 4;
  int tid = threadIdx.x;

  for (int t = tid; t < 1664; t += 384) {
    int row = t / 208, rem = t % 208, px = rem >> 2, g = rem & 3;
    int4 v = make_int4(0,0,0,0);
    if (px < 44)
      v = *(const int4*)(in + (((size_t)n*44 + oy0 + row)*44 + px)*32 + g*8);
    int sb = ((row*52 + px) << 6) + ((g ^ ((px >> 1) & 3)) << 4);
    *(int4*)(lds + sb) = v;
  }
  __syncthreads();

  int wv = tid >> 6, lane = tid & 63;
  int rp = wv & 1, cg = wv >> 1;
  int col = lane & 15, kq = lane >> 4;
  int ixb = cg*16 + col;

  f32x4 acc0, acc1;
#pragma unroll
  for (int i = 0; i < 4; ++i) { acc0[i] = 0.f; acc1[i] = 0.f; }

#pragma unroll
  for (int ks = 0; ks < 25; ++ks) {
    const int ky = ks/5, kx = ks%5;
    short8 av = *(const short8*)(wp + ks*512 + lane*8);
    int ix = ixb + kx;
    int g  = kq ^ ((ix >> 1) & 3);
    {
      int row = 2*rp + 0 + ky;
      short8 bv = *(const short8*)(lds + ((row*52 + ix) << 6) + (g << 4));
      acc0 = __builtin_amdgcn_mfma_f32_16x16x32_bf16(av, bv, acc0, 0, 0, 0);
    }
    {
      int row = 2*rp + 1 + ky;
      short8 bv = *(const short8*)(lds + ((row*52 + ix) << 6) + (g << 4));
      acc1 = __builtin_amdgcn_mfma_f32_16x16x32_bf16(av, bv, acc1, 0, 0, 0);
    }
  }
  __syncthreads();

  {
    __hip_bfloat16 pv[4];
#pragma unroll
    for (int r = 0; r < 4; ++r) {
      float m = fmaxf(acc0[r], acc1[r]);
      float o = __shfl_xor(m, 1);
      float p = fmaxf(m, o);
      int oc = kq*4 + r;
      pv[r] = __float2bfloat16(fmaxf(p + bias[oc], 0.f));
    }
    if ((lane & 1) == 0) {
      int pl = col >> 1;
      *(uint2*)(lds + wv*256 + pl*32 + kq*8) = *(const uint2*)pv;
    }
  }
  __syncthreads();

  if (tid < 96) {
    int byte = tid * 16;
    int w = byte >> 8, r = byte & 255;
    int pl = r >> 5, half = (r & 31) >> 4;
    int pr = rg*2 + (w & 1);
    int pc = (w >> 1)*8 + pl;
    if (pc < 20) {
      *(int4*)(out + (((size_t)n*20 + pr)*20 + pc)*16 + half*8) =
          *(const int4*)(lds + byte);
    }
  }
}

// ------------------------------------------------------------------------ fc1
__global__ __launch_bounds__(256) void fc1_partial(
    const __hip_bfloat16* __restrict__ x, const __hip_bfloat16* __restrict__ w,
    float* __restrict__ part)
{
  constexpr int KC = 6400 / 16;   // 400
  __shared__ float xl[128][16];
  __shared__ float wlds[32][17];
  int nt = blockIdx.x, ks = blockIdx.y;
  int k0 = ks * KC;
  int nl = threadIdx.x & 31;
  int mg = threadIdx.x >> 5;
  float acc[16];
#pragma unroll
  for (int j = 0; j < 16; ++j) acc[j] = 0.f;

  for (int kb = 0; kb < KC; kb += 16) {
    for (int t = threadIdx.x; t < 128*16; t += 256) {
      int m = t >> 4, kk = t & 15;
      xl[m][kk] = __bfloat162float(x[(size_t)m*6400 + k0 + kb + kk]);
    }
    for (int t = threadIdx.x; t < 32*16; t += 256) {
      int nn = t >> 4, kk = t & 15;
      wlds[nn][kk] = __bfloat162float(w[(size_t)(nt*32 + nn)*6400 + k0 + kb + kk]);
    }
    __syncthreads();
#pragma unroll
    for (int kk = 0; kk < 16; ++kk) {
      float wvv = wlds[nl][kk];
#pragma unroll
      for (int j = 0; j < 16; ++j)
        acc[j] += xl[mg + 8*j][kk] * wvv;
    }
    __syncthreads();
  }
#pragma unroll
  for (int j = 0; j < 16; ++j) {
    int m = mg + 8*j;
    part[((size_t)ks*128 + m)*512 + nt*32 + nl] = acc[j];
  }
}

__global__ __launch_bounds__(256) void fc1_reduce(
    const float* __restrict__ part, const float* __restrict__ bias,
    float* __restrict__ y4)
{
  int o = blockIdx.x*256 + threadIdx.x;
  int nn = o & 511;
  float s = 0.f;
#pragma unroll
  for (int ks = 0; ks < 16; ++ks)
    s += part[(size_t)ks*65536 + o];
  y4[o] = fmaxf(s + bias[nn], 0.f);
}

// ------------------------------------------------------------------------ fc2
__global__ __launch_bounds__(256) void fc2_kernel(
    const float* __restrict__ y4, const float* __restrict__ w2,
    const float* __restrict__ b2, float* __restrict__ pred)
{
  int o = blockIdx.x*256 + threadIdx.x;
  if (o >= 1280) return;
  int m = o / 10, c = o % 10;
  float s = 0.f;
  const float* yr = y4 + (size_t)m*512;
  const float* wr = w2 + (size_t)c*512;
#pragma unroll 8
  for (int k = 0; k < 512; ++k) s += yr[k]*wr[k];
  pred[o] = s + b2[c];
}

// -------------------------------------------------------------------- epilogue
__global__ void finalize_kernel(const float* __restrict__ lossAcc,
                                float* __restrict__ out)
{
  out[1280] = 2.f * (*lossAcc) / 10616832.f;
  out[84935937] = 0.f;
}

// ---------------------------------------------------------------------- launch
extern "C" void kernel_launch(void* const* d_in, const int* in_sizes, int n_in,
                              void* d_out, int out_size, void* d_ws, size_t ws_size,
                              hipStream_t stream)
{
  const float* x   = (const float*)d_in[0];
  const float* cb  = (const float*)d_in[1];
  const float* w1  = (const float*)d_in[2];
  const float* b1  = (const float*)d_in[3];
  const float* w2  = (const float*)d_in[4];
  const float* b2  = (const float*)d_in[5];
  const float* w3  = (const float*)d_in[6];
  const float* b3  = (const float*)d_in[7];
  const float* wf1 = (const float*)d_in[8];
  const float* bf1 = (const float*)d_in[9];
  const float* wf2 = (const float*)d_in[10];
  const float* bf2 = (const float*)d_in[11];

  float* out = (float*)d_out;
  char*  ws  = (char*)d_ws;

  float*          xq   = (float*)         (ws + 0);
  __hip_bfloat16* y1   = (__hip_bfloat16*)(ws + 14155776);
  __hip_bfloat16* y2   = (__hip_bfloat16*)(ws + 83492864);
  __hip_bfloat16* y3   = (__hip_bfloat16*)(ws + 99352576);
  float*          part = (float*)         (ws + 104267776);
  __hip_bfloat16* cbp  = (__hip_bfloat16*)(ws + 104267776);  // dead before fc1
  float*          y4   = (float*)         (ws + 108462080);
  __hip_bfloat16* wp2  = (__hip_bfloat16*)(ws + 108724224);
  __hip_bfloat16* wp3  = (__hip_bfloat16*)(ws + 108775424);
  float*          cbn2 = (float*)         (ws + 108801024);
  float*          loss = (float*)         (ws + 108802560);
  __hip_bfloat16* wf1p = (__hip_bfloat16*)(ws + 108802624);

  hipMemsetAsync(loss, 0, sizeof(float), stream);

  pack_w_kernel<<<100, 256, 0, stream>>>(w2, w3, cb, wp2, wp3, cbn2, cbp);
  pack_wf1<<<12800, 256, 0, stream>>>(wf1, wf1p);

  quant_mfma<<<3456, 256, 0, stream>>>(x, cb, cbp, cbn2, out + 1281, xq, loss);

  conv1_kernel<<<dim3(36, 128), 512, 0, stream>>>(xq, w1, b1, y1);
  conv2_mfma<<<dim3(22, 128), 384, 0, stream>>>(y1, wp2, b2, y2);
  conv3_mfma<<<dim3(10, 128), 384, 0, stream>>>(y2, wp3, b3, y3);

  fc1_partial<<<dim3(16, 16), 256, 0, stream>>>(y3, wf1p, part);
  fc1_reduce<<<256, 256, 0, stream>>>(part, bf1, y4);
  fc2_kernel<<<5, 256, 0, stream>>>(y4, wf2, bf2, out);

  finalize_kernel<<<1, 1, 0, stream>>>(loss, out);
}

// Round 18
// 347.966 us; speedup vs baseline: 1.4265x; 1.1459x over previous
//
#include <hip/hip_runtime.h>
#include <hip/hip_bf16.h>

// ---------------------------------------------------------------------------
// CNN_quantize round 16 (2nd resubmit after infra failures): conv1 converted
// to MFMA implicit-GEMM (was direct f32 VALU, est ~90us, largest tail item).
// K = 5 ky-steps x 16 (kx*3+ic, 15 real + 1 pad); im2col built in LDS per
// tile; one wave per out row. quant_mfma + conv2/conv3 + fc path identical
// to round 15.
//
// Output layout (floats): [0,1280) pred; [1280] extra_loss;
// [1281,1281+84934656) att(3,221184,128); [84935937] contrastive.
//
// Workspace (byte offsets):
//   xq    f32  @ 0           14,155,776 B
//   y1    bf16 @ 14,155,776  69,337,088 B   (128,92,92,32) NHWC
//   y2    bf16 @ 83,492,864  15,859,712 B   (128,44,44,32) NHWC
//   y3    bf16 @ 99,352,576   1,638,400 B   (128,20,20,16) NHWC
//   part  f32  @ 104,267,776  4,194,304 B   (cbp @ +0 12,288 B and wp1
//                                            @ +16,384 5,120 B live here
//                                            until fc1_partial overwrites)
//   y4    f32  @ 108,462,080    262,144 B
//   wp2   bf16 @ 108,724,224     51,200 B
//   wp3   bf16 @ 108,775,424     25,600 B
//   cbn2  f32  @ 108,801,024      1,536 B
//   loss  f32  @ 108,802,560          4 B
//   wf1p  bf16 @ 108,802,624   6,553,600 B
// ---------------------------------------------------------------------------

#define NP 221184

typedef __attribute__((ext_vector_type(8)))  short  short8;   // 8 bf16
typedef __attribute__((ext_vector_type(16))) float  f32x16;
typedef __attribute__((ext_vector_type(4)))  float  f32x4;

// ---------------------------------------------------------------------- quant
// r15 quant_mfma verbatim (measured ~158us).
__global__ __launch_bounds__(256) void quant_mfma(
    const float* __restrict__ x, const float* __restrict__ cb,
    const __hip_bfloat16* __restrict__ cbp, const float* __restrict__ cbn2,
    float* __restrict__ att, float* __restrict__ xq, float* __restrict__ lossAcc)
{
  __shared__ float stage[4][64][32];   // 32 KB granule-swizzled
  __shared__ float sred[4][64];
  __shared__ float mred[4][64];
  __shared__ int   ired[4][64];

  const int tid  = threadIdx.x;
  const int wv   = tid >> 6;
  const int lane = tid & 63;
  const int col  = lane & 31;
  const int hi   = lane >> 5;
  const int l7   = lane & 7;
  const int n0   = blockIdx.x * 64;
  const int n    = n0 + lane;

  const float4* xp4 = (const float4*)(x + (size_t)n*16);
  float4 xa = xp4[0], xb = xp4[1], xc = xp4[2], xd = xp4[3];
  float xv[16] = {xa.x,xa.y,xa.z,xa.w, xb.x,xb.y,xb.z,xb.w,
                  xc.x,xc.y,xc.z,xc.w, xd.x,xd.y,xd.z,xd.w};

  short8 bf0, bf1;
  {
    __attribute__((aligned(16))) __hip_bfloat16 tmp[8];
    const float* p0 = x + (size_t)(n0 + col)*16 + hi*8;
    float4 u = *(const float4*)p0, v = *(const float4*)(p0 + 4);
    tmp[0]=__float2bfloat16(u.x); tmp[1]=__float2bfloat16(u.y);
    tmp[2]=__float2bfloat16(u.z); tmp[3]=__float2bfloat16(u.w);
    tmp[4]=__float2bfloat16(v.x); tmp[5]=__float2bfloat16(v.y);
    tmp[6]=__float2bfloat16(v.z); tmp[7]=__float2bfloat16(v.w);
    bf0 = *(const short8*)tmp;
    const float* p1 = x + (size_t)(n0 + 32 + col)*16 + hi*8;
    float4 u1 = *(const float4*)p1, v1 = *(const float4*)(p1 + 4);
    tmp[0]=__float2bfloat16(u1.x); tmp[1]=__float2bfloat16(u1.y);
    tmp[2]=__float2bfloat16(u1.z); tmp[3]=__float2bfloat16(u1.w);
    tmp[4]=__float2bfloat16(v1.x); tmp[5]=__float2bfloat16(v1.y);
    tmp[6]=__float2bfloat16(v1.z); tmp[7]=__float2bfloat16(v1.w);
    bf1 = *(const short8*)tmp;
  }

  float xqacc[16];
#pragma unroll
  for (int d = 0; d < 16; ++d) xqacc[d] = 0.f;
  float lossLocal = 0.f;

#pragma unroll 1
  for (int g = 0; g < 3; ++g) {
    const float* c2g = cbn2 + g*128 + wv*32;

    short8 af = *(const short8*)(cbp + ((size_t)(g*4 + wv)*64 + lane)*8);
    f32x16 zacc;
#pragma unroll
    for (int i = 0; i < 16; ++i) zacc[i] = 0.f;
    f32x16 acc0 = __builtin_amdgcn_mfma_f32_32x32x16_bf16(af, bf0, zacc, 0, 0, 0);
    f32x16 acc1 = __builtin_amdgcn_mfma_f32_32x32x16_bf16(af, bf1, zacc, 0, 0, 0);

    float e0[16], e1[16];
    float s0 = 0.f, s1 = 0.f;
    float bm0 = 3.4e38f, bm1 = 3.4e38f;
    int   bi0 = 0, bi1 = 0;
#pragma unroll
    for (int r = 0; r < 16; ++r) {
      const int row = (r & 3) + 8*(r >> 2) + 4*hi;
      const int k   = wv*32 + row;
      float c2 = c2g[row];
      float t0 = fmaf(-2.f, acc0[r], c2);
      float t1 = fmaf(-2.f, acc1[r], c2);
      float q0 = __expf(-t0);
      float q1 = __expf(-t1);
      e0[r] = q0; e1[r] = q1;
      s0 += q0; s1 += q1;
      if (t0 < bm0 || (t0 == bm0 && k < bi0)) { bm0 = t0; bi0 = k; }
      if (t1 < bm1 || (t1 == bm1 && k < bi1)) { bm1 = t1; bi1 = k; }
    }

    s0 += __shfl_xor(s0, 32);
    s1 += __shfl_xor(s1, 32);
    {
      float om = __shfl_xor(bm0, 32); int oi = __shfl_xor(bi0, 32);
      if (om < bm0 || (om == bm0 && oi < bi0)) { bm0 = om; bi0 = oi; }
      om = __shfl_xor(bm1, 32); oi = __shfl_xor(bi1, 32);
      if (om < bm1 || (om == bm1 && oi < bi1)) { bm1 = om; bi1 = oi; }
    }
    float sM  = hi ? s1 : s0;
    float bmM = hi ? bm1 : bm0;
    int   biM = hi ? bi1 : bi0;

    __syncthreads();
    sred[wv][lane] = sM;
    mred[wv][lane] = bmM;
    ired[wv][lane] = biM;
    __syncthreads();
    float stot = (sred[0][lane] + sred[1][lane]) + (sred[2][lane] + sred[3][lane]);
    float bm = mred[0][lane]; int bi = ired[0][lane];
#pragma unroll
    for (int w = 1; w < 4; ++w) {
      float m2 = mred[w][lane];
      int   i2 = ired[w][lane];
      if (m2 < bm) { bm = m2; bi = i2; }
    }
    float invL = 1.f / stot;
    float inv0 = __shfl(invL, col);
    float inv1 = __shfl(invL, col + 32);

#pragma unroll
    for (int run = 0; run < 4; ++run) {
      const int gl = run*2 + hi;
      f32x4 v;
      v[0] = e0[run*4+0]*inv0; v[1] = e0[run*4+1]*inv0;
      v[2] = e0[run*4+2]*inv0; v[3] = e0[run*4+3]*inv0;
      *(f32x4*)&stage[wv][col][(gl ^ (col & 7)) << 2] = v;
      const int p1 = col + 32;
      f32x4 w4;
      w4[0] = e1[run*4+0]*inv1; w4[1] = e1[run*4+1]*inv1;
      w4[2] = e1[run*4+2]*inv1; w4[3] = e1[run*4+3]*inv1;
      *(f32x4*)&stage[wv][p1][(gl ^ (p1 & 7)) << 2] = w4;
    }
    __builtin_amdgcn_wave_barrier();

    {
      const int pr = lane >> 3;
      const int pg = l7 ^ pr;
      float* ab = att + ((size_t)g*NP + n0)*128 + wv*32;
#pragma unroll
      for (int i = 0; i < 8; ++i) {
        int p = pr + 8*i;
        f32x4 v = *(const f32x4*)&stage[wv][p][pg << 2];
        __builtin_nontemporal_store(v, (f32x4*)(ab + (size_t)p*128 + (l7 << 2)));
      }
    }
    __builtin_amdgcn_wave_barrier();

    if (wv == 0) {
      const float4* qr = (const float4*)(cb + g*2048 + bi*16);
      float4 q0 = qr[0], q1 = qr[1], q2 = qr[2], q3 = qr[3];
      float qv[16] = {q0.x,q0.y,q0.z,q0.w, q1.x,q1.y,q1.z,q1.w,
                      q2.x,q2.y,q2.z,q2.w, q3.x,q3.y,q3.z,q3.w};
#pragma unroll
      for (int d = 0; d < 16; ++d) {
        xqacc[d] += qv[d];
        float e = qv[d] - xv[d];
        lossLocal += e*e;
      }
    }
  }

  if (wv == 0) {
    float4* xqo = (float4*)(xq + (size_t)n*16);
    const float third = 1.f/3.f;
    xqo[0] = make_float4(xqacc[0]*third, xqacc[1]*third, xqacc[2]*third, xqacc[3]*third);
    xqo[1] = make_float4(xqacc[4]*third, xqacc[5]*third, xqacc[6]*third, xqacc[7]*third);
    xqo[2] = make_float4(xqacc[8]*third, xqacc[9]*third, xqacc[10]*third, xqacc[11]*third);
    xqo[3] = make_float4(xqacc[12]*third, xqacc[13]*third, xqacc[14]*third, xqacc[15]*third);
#pragma unroll
    for (int off = 32; off > 0; off >>= 1) lossLocal += __shfl_xor(lossLocal, off);
    if (lane == 0) atomicAdd(lossAcc, lossLocal);
  }
}

// ----------------------------------------------------------------- weight pack
// wp2/wp3/cbn2/cbp as r15; wp1 (conv1 A-frags):
// wp1[ky*512 + l*8 + j]: oc=l&31, idx=(l>>5)*8+j; idx<15 -> w1[oc][idx%3][ky][idx/3]
__global__ __launch_bounds__(256) void pack_w_kernel(
    const float* __restrict__ w1, const float* __restrict__ w2,
    const float* __restrict__ w3, const float* __restrict__ cb,
    __hip_bfloat16* __restrict__ p1, __hip_bfloat16* __restrict__ p2,
    __hip_bfloat16* __restrict__ p3,
    float* __restrict__ cbn2, __hip_bfloat16* __restrict__ cbp)
{
  int t = blockIdx.x*256 + threadIdx.x;
  if (t < 25600) {
    int ks = t >> 9, l = (t >> 3) & 63, j = t & 7;
    int ky = ks/10, kx = (ks%10)>>1, ih = ks & 1;
    int oc = l & 31, kh = l >> 5;
    int ic = ih*16 + kh*8 + j;
    p2[t] = __float2bfloat16(w2[((oc*32 + ic)*5 + ky)*5 + kx]);
  }
  if (t < 12800) {
    int ks = t >> 9, l = (t >> 3) & 63, j = t & 7;
    int ky = ks/5, kx = ks%5;
    int oc = l & 15, kh = l >> 4;
    int ic = kh*8 + j;
    p3[t] = __float2bfloat16(w3[((oc*32 + ic)*5 + ky)*5 + kx]);
  }
  if (t < 384) {
    float s = 0.f;
#pragma unroll
    for (int d = 0; d < 16; ++d) { float v = cb[t*16 + d]; s += v*v; }
    cbn2[t] = s;
  }
  if (t < 6144) {
    int g = t >> 11, r = t & 2047;
    int ct = r >> 9, l = (r >> 3) & 63, j = r & 7;
    int code = ct*32 + (l & 31);
    int d = (l >> 5)*8 + j;
    cbp[t] = __float2bfloat16(cb[((size_t)g*128 + code)*16 + d]);
  }
  if (t < 2560) {
    int ky = t >> 9, l = (t >> 3) & 63, j = t & 7;
    int oc = l & 31, kh = l >> 5;
    int idx = kh*8 + j;
    float v = 0.f;
    if (idx < 15) {
      int kx = idx / 3, ic = idx % 3;
      v = w1[((oc*3 + ic)*5 + ky)*5 + kx];
    }
    p1[t] = __float2bfloat16(v);
  }
}

// fc1 weights -> NHWC k-order bf16
__global__ __launch_bounds__(256) void pack_wf1(
    const float* __restrict__ wf1, __hip_bfloat16* __restrict__ p)
{
  int t = blockIdx.x*256 + threadIdx.x;
  if (t < 512*6400) {
    int nn = t / 6400, k = t % 6400;
    int c = k & 15, yx = k >> 4;
    p[t] = __float2bfloat16(wf1[(size_t)nn*6400 + c*400 + yx]);
  }
}

// ------------------------------------------------------------------ conv1 MFMA
// (128,3,96,96) f32 NCHW -> (128,92,92,32) bf16 NHWC, relu.
// Grid (36 = 3x x 12y, 128 n), 512 thr = 8 waves; wave = one out row.
// Tile 8 rows x 32 cols. K = 5 ky-steps of 16 (idx = kx*3+ic; 15 real, 1 pad).
__global__ __launch_bounds__(512) void conv1_mfma(
    const float* __restrict__ in, const __hip_bfloat16* __restrict__ wp1,
    const float* __restrict__ bias, __hip_bfloat16* __restrict__ out)
{
  __shared__ __align__(16) float ins[3][12][36];              //  5184 B
  __shared__ __align__(16) __hip_bfloat16 imcol[12][32][24];  // 18432 B (48B slots)
  __shared__ __align__(16) __hip_bfloat16 tb[8][32][40];      // 20480 B (80B slots)

  int tile = blockIdx.x;
  int tx0 = (tile % 3) * 32, ty0 = (tile / 3) * 8;
  int n = blockIdx.y;

  // stage input tile (f32)
  for (int t = threadIdx.x; t < 3*12*36; t += 512) {
    int ic = t / (12*36); int r = t % (12*36); int ry = r / 36, rx = r % 36;
    int gy = ty0 + ry, gx = tx0 + rx;
    float v = 0.f;
    if (gy < 96 && gx < 96)
      v = in[(((size_t)n*3 + ic)*96 + gy)*96 + gx];
    ins[ic][ry][rx] = v;
  }
  __syncthreads();

  // build im2col: imcol[r][x][idx] = ins[idx%3][r][x + idx/3], idx<15; [15]=0
  for (int t = threadIdx.x; t < 12*32*15; t += 512) {
    int idx = t % 15; int p = t / 15; int x = p & 31; int r = p >> 5;
    int kx = idx / 3, ic = idx - kx*3;
    imcol[r][x][idx] = __float2bfloat16(ins[ic][r][x + kx]);
  }
  for (int t = threadIdx.x; t < 12*32; t += 512)
    imcol[t >> 5][t & 31][15] = __float2bfloat16(0.f);
  __syncthreads();

  const int wave = threadIdx.x >> 6;   // out row within tile
  const int lane = threadIdx.x & 63;
  const int col  = lane & 31;          // out col within tile
  const int kh   = lane >> 5;

  f32x16 acc;
#pragma unroll
  for (int i = 0; i < 16; ++i) acc[i] = 0.f;

#pragma unroll
  for (int ky = 0; ky < 5; ++ky) {
    short8 a = *(const short8*)(wp1 + ky*512 + lane*8);
    short8 b = *(const short8*)&imcol[wave + ky][col][kh*8];
    acc = __builtin_amdgcn_mfma_f32_32x32x16_bf16(a, b, acc, 0, 0, 0);
  }

  // epilogue: bias+relu -> tb[wave][col][oc]
#pragma unroll
  for (int run = 0; run < 4; ++run) {
    __hip_bfloat16 pv[4];
#pragma unroll
    for (int j = 0; j < 4; ++j) {
      int r = run*4 + j;
      int oc = j + 8*run + 4*kh;
      pv[j] = __float2bfloat16(fmaxf(acc[r] + bias[oc], 0.f));
    }
    *(uint2*)&tb[wave][col][8*run + 4*kh] = *(const uint2*)pv;
  }
  __syncthreads();

  // coalesced NHWC store: 1024 int4s (8 rows x 32 px x 4 quads)
  for (int t = threadIdx.x; t < 1024; t += 512) {
    int w = t >> 7, rem = t & 127, px = rem >> 2, q = rem & 3;
    int gy = ty0 + w, gx = tx0 + px;
    if (gy < 92 && gx < 92) {
      *(int4*)(out + ((size_t)((n*92 + gy)*92 + gx))*32 + q*8) =
          *(const int4*)&tb[w][px][q*8];
    }
  }
}

// ------------------------------------------------------------------ conv2 MFMA
__global__ __launch_bounds__(384) void conv2_mfma(
    const __hip_bfloat16* __restrict__ in, const __hip_bfloat16* __restrict__ wp,
    const float* __restrict__ bias, __hip_bfloat16* __restrict__ out)
{
  __shared__ __align__(16) char lds[8*100*64];   // 51200 B

  int n = blockIdx.y, rg = blockIdx.x;
  int oy0 = rg * 4;
  int tid = threadIdx.x;

  for (int t = tid; t < 3200; t += 384) {
    int row = t / 400, rem = t % 400, px = rem >> 2, g = rem & 3;
    int4 v = make_int4(0,0,0,0);
    if (px < 92)
      v = *(const int4*)(in + (((size_t)n*92 + oy0 + row)*92 + px)*32 + g*8);
    int sb = ((row*100 + px) << 6) + ((g ^ ((px >> 1) & 3)) << 4);
    *(int4*)(lds + sb) = v;
  }
  __syncthreads();

  int wv = tid >> 6, lane = tid & 63;
  int rp = wv & 1, cg = wv >> 1;
  int col = lane & 31, khalf = lane >> 5;
  int ixb = cg*32 + col;

  f32x16 acc0, acc1;
#pragma unroll
  for (int i = 0; i < 16; ++i) { acc0[i] = 0.f; acc1[i] = 0.f; }

#pragma unroll
  for (int ks = 0; ks < 50; ++ks) {
    const int ky = ks/10, kx = (ks%10)>>1, ih = ks & 1;
    short8 av = *(const short8*)(wp + ks*512 + lane*8);
    int ix = ixb + kx;
    int g  = (ih*2 + khalf) ^ ((ix >> 1) & 3);
    {
      int row = 2*rp + 0 + ky;
      short8 bv = *(const short8*)(lds + ((row*100 + ix) << 6) + (g << 4));
      acc0 = __builtin_amdgcn_mfma_f32_32x32x16_bf16(av, bv, acc0, 0, 0, 0);
    }
    {
      int row = 2*rp + 1 + ky;
      short8 bv = *(const short8*)(lds + ((row*100 + ix) << 6) + (g << 4));
      acc1 = __builtin_amdgcn_mfma_f32_32x32x16_bf16(av, bv, acc1, 0, 0, 0);
    }
  }
  __syncthreads();

  {
#pragma unroll
    for (int rq = 0; rq < 4; ++rq) {
      __hip_bfloat16 pv[4];
#pragma unroll
      for (int rr = 0; rr < 4; ++rr) {
        int r = rq*4 + rr;
        float m = fmaxf(acc0[r], acc1[r]);
        float o = __shfl_xor(m, 1);
        float p = fmaxf(m, o);
        int oc = (r & 3) + 8*(r >> 2) + 4*khalf;
        pv[rr] = __float2bfloat16(fmaxf(p + bias[oc], 0.f));
      }
      if ((lane & 1) == 0) {
        int pl = col >> 1;
        *(uint2*)(lds + wv*1024 + pl*64 + (8*rq + 4*khalf)*2) = *(const uint2*)pv;
      }
    }
  }
  __syncthreads();

  if (tid < 384) {
    int byte = tid * 16;
    int w = byte >> 10, r = byte & 1023;
    int pl = r >> 6, ocq = (r & 63) >> 4;
    int pr = rg*2 + (w & 1);
    int pc = (w >> 1)*16 + pl;
    if (pc < 44) {
      *(int4*)(out + (((size_t)n*44 + pr)*44 + pc)*32 + ocq*8) =
          *(const int4*)(lds + byte);
    }
  }
}

// ------------------------------------------------------------------ conv3 MFMA
__global__ __launch_bounds__(384) void conv3_mfma(
    const __hip_bfloat16* __restrict__ in, const __hip_bfloat16* __restrict__ wp,
    const float* __restrict__ bias, __hip_bfloat16* __restrict__ out)
{
  __shared__ __align__(16) char lds[8*52*64];   // 26624 B

  int n = blockIdx.y, rg = blockIdx.x;
  int oy0 = rg * 4;
  int tid = threadIdx.x;

  for (int t = tid; t < 1664; t += 384) {
    int row = t / 208, rem = t % 208, px = rem >> 2, g = rem & 3;
    int4 v = make_int4(0,0,0,0);
    if (px < 44)
      v = *(const int4*)(in + (((size_t)n*44 + oy0 + row)*44 + px)*32 + g*8);
    int sb = ((row*52 + px) << 6) + ((g ^ ((px >> 1) & 3)) << 4);
    *(int4*)(lds + sb) = v;
  }
  __syncthreads();

  int wv = tid >> 6, lane = tid & 63;
  int rp = wv & 1, cg = wv >> 1;
  int col = lane & 15, kq = lane >> 4;
  int ixb = cg*16 + col;

  f32x4 acc0, acc1;
#pragma unroll
  for (int i = 0; i < 4; ++i) { acc0[i] = 0.f; acc1[i] = 0.f; }

#pragma unroll
  for (int ks = 0; ks < 25; ++ks) {
    const int ky = ks/5, kx = ks%5;
    short8 av = *(const short8*)(wp + ks*512 + lane*8);
    int ix = ixb + kx;
    int g  = kq ^ ((ix >> 1) & 3);
    {
      int row = 2*rp + 0 + ky;
      short8 bv = *(const short8*)(lds + ((row*52 + ix) << 6) + (g << 4));
      acc0 = __builtin_amdgcn_mfma_f32_16x16x32_bf16(av, bv, acc0, 0, 0, 0);
    }
    {
      int row = 2*rp + 1 + ky;
      short8 bv = *(const short8*)(lds + ((row*52 + ix) << 6) + (g << 4));
      acc1 = __builtin_amdgcn_mfma_f32_16x16x32_bf16(av, bv, acc1, 0, 0, 0);
    }
  }
  __syncthreads();

  {
    __hip_bfloat16 pv[4];
#pragma unroll
    for (int r = 0; r < 4; ++r) {
      float m = fmaxf(acc0[r], acc1[r]);
      float o = __shfl_xor(m, 1);
      float p = fmaxf(m, o);
      int oc = kq*4 + r;
      pv[r] = __float2bfloat16(fmaxf(p + bias[oc], 0.f));
    }
    if ((lane & 1) == 0) {
      int pl = col >> 1;
      *(uint2*)(lds + wv*256 + pl*32 + kq*8) = *(const uint2*)pv;
    }
  }
  __syncthreads();

  if (tid < 96) {
    int byte = tid * 16;
    int w = byte >> 8, r = byte & 255;
    int pl = r >> 5, half = (r & 31) >> 4;
    int pr = rg*2 + (w & 1);
    int pc = (w >> 1)*8 + pl;
    if (pc < 20) {
      *(int4*)(out + (((size_t)n*20 + pr)*20 + pc)*16 + half*8) =
          *(const int4*)(lds + byte);
    }
  }
}

// ------------------------------------------------------------------------ fc1
__global__ __launch_bounds__(256) void fc1_partial(
    const __hip_bfloat16* __restrict__ x, const __hip_bfloat16* __restrict__ w,
    float* __restrict__ part)
{
  constexpr int KC = 6400 / 16;   // 400
  __shared__ float xl[128][16];
  __shared__ float wlds[32][17];
  int nt = blockIdx.x, ks = blockIdx.y;
  int k0 = ks * KC;
  int nl = threadIdx.x & 31;
  int mg = threadIdx.x >> 5;
  float acc[16];
#pragma unroll
  for (int j = 0; j < 16; ++j) acc[j] = 0.f;

  for (int kb = 0; kb < KC; kb += 16) {
    for (int t = threadIdx.x; t < 128*16; t += 256) {
      int m = t >> 4, kk = t & 15;
      xl[m][kk] = __bfloat162float(x[(size_t)m*6400 + k0 + kb + kk]);
    }
    for (int t = threadIdx.x; t < 32*16; t += 256) {
      int nn = t >> 4, kk = t & 15;
      wlds[nn][kk] = __bfloat162float(w[(size_t)(nt*32 + nn)*6400 + k0 + kb + kk]);
    }
    __syncthreads();
#pragma unroll
    for (int kk = 0; kk < 16; ++kk) {
      float wvv = wlds[nl][kk];
#pragma unroll
      for (int j = 0; j < 16; ++j)
        acc[j] += xl[mg + 8*j][kk] * wvv;
    }
    __syncthreads();
  }
#pragma unroll
  for (int j = 0; j < 16; ++j) {
    int m = mg + 8*j;
    part[((size_t)ks*128 + m)*512 + nt*32 + nl] = acc[j];
  }
}

__global__ __launch_bounds__(256) void fc1_reduce(
    const float* __restrict__ part, const float* __restrict__ bias,
    float* __restrict__ y4)
{
  int o = blockIdx.x*256 + threadIdx.x;
  int nn = o & 511;
  float s = 0.f;
#pragma unroll
  for (int ks = 0; ks < 16; ++ks)
    s += part[(size_t)ks*65536 + o];
  y4[o] = fmaxf(s + bias[nn], 0.f);
}

// ------------------------------------------------------------------------ fc2
__global__ __launch_bounds__(256) void fc2_kernel(
    const float* __restrict__ y4, const float* __restrict__ w2,
    const float* __restrict__ b2, float* __restrict__ pred)
{
  int o = blockIdx.x*256 + threadIdx.x;
  if (o >= 1280) return;
  int m = o / 10, c = o % 10;
  float s = 0.f;
  const float* yr = y4 + (size_t)m*512;
  const float* wr = w2 + (size_t)c*512;
#pragma unroll 8
  for (int k = 0; k < 512; ++k) s += yr[k]*wr[k];
  pred[o] = s + b2[c];
}

// -------------------------------------------------------------------- epilogue
__global__ void finalize_kernel(const float* __restrict__ lossAcc,
                                float* __restrict__ out)
{
  out[1280] = 2.f * (*lossAcc) / 10616832.f;
  out[84935937] = 0.f;
}

// ---------------------------------------------------------------------- launch
extern "C" void kernel_launch(void* const* d_in, const int* in_sizes, int n_in,
                              void* d_out, int out_size, void* d_ws, size_t ws_size,
                              hipStream_t stream)
{
  const float* x   = (const float*)d_in[0];
  const float* cb  = (const float*)d_in[1];
  const float* w1  = (const float*)d_in[2];
  const float* b1  = (const float*)d_in[3];
  const float* w2  = (const float*)d_in[4];
  const float* b2  = (const float*)d_in[5];
  const float* w3  = (const float*)d_in[6];
  const float* b3  = (const float*)d_in[7];
  const float* wf1 = (const float*)d_in[8];
  const float* bf1 = (const float*)d_in[9];
  const float* wf2 = (const float*)d_in[10];
  const float* bf2 = (const float*)d_in[11];

  float* out = (float*)d_out;
  char*  ws  = (char*)d_ws;

  float*          xq   = (float*)         (ws + 0);
  __hip_bfloat16* y1   = (__hip_bfloat16*)(ws + 14155776);
  __hip_bfloat16* y2   = (__hip_bfloat16*)(ws + 83492864);
  __hip_bfloat16* y3   = (__hip_bfloat16*)(ws + 99352576);
  float*          part = (float*)         (ws + 104267776);
  __hip_bfloat16* cbp  = (__hip_bfloat16*)(ws + 104267776);  // dead before fc1
  __hip_bfloat16* wp1  = (__hip_bfloat16*)(ws + 104284160);  // dead before fc1
  float*          y4   = (float*)         (ws + 108462080);
  __hip_bfloat16* wp2  = (__hip_bfloat16*)(ws + 108724224);
  __hip_bfloat16* wp3  = (__hip_bfloat16*)(ws + 108775424);
  float*          cbn2 = (float*)         (ws + 108801024);
  float*          loss = (float*)         (ws + 108802560);
  __hip_bfloat16* wf1p = (__hip_bfloat16*)(ws + 108802624);

  hipMemsetAsync(loss, 0, sizeof(float), stream);

  pack_w_kernel<<<100, 256, 0, stream>>>(w1, w2, w3, cb, wp1, wp2, wp3, cbn2, cbp);
  pack_wf1<<<12800, 256, 0, stream>>>(wf1, wf1p);

  quant_mfma<<<3456, 256, 0, stream>>>(x, cb, cbp, cbn2, out + 1281, xq, loss);

  conv1_mfma<<<dim3(36, 128), 512, 0, stream>>>(xq, wp1, b1, y1);
  conv2_mfma<<<dim3(22, 128), 384, 0, stream>>>(y1, wp2, b2, y2);
  conv3_mfma<<<dim3(10, 128), 384, 0, stream>>>(y2, wp3, b3, y3);

  fc1_partial<<<dim3(16, 16), 256, 0, stream>>>(y3, wf1p, part);
  fc1_reduce<<<256, 256, 0, stream>>>(part, bf1, y4);
  fc2_kernel<<<5, 256, 0, stream>>>(y4, wf2, bf2, out);

  finalize_kernel<<<1, 1, 0, stream>>>(loss, out);
}